// Round 1
// 633.507 us; speedup vs baseline: 1.0244x; 1.0244x over previous
//
#include <hip/hip_runtime.h>

#define B_SZ   2048
#define V_SZ   50257
#define TD     2048
#define NIN    128
#define NOUT   128
#define NRECV  1628
#define KDEG   45
#define KPAD   48
#define HPL    300
#define VALSN  1632   // 1630 rounded up

typedef __bf16 bf16x8 __attribute__((ext_vector_type(8)));
typedef float  floatx16 __attribute__((ext_vector_type(16)));

__device__ __forceinline__ unsigned short f2bf(float f) {
  unsigned u = __float_as_uint(f);
  u += 0x7fffu + ((u >> 16) & 1u);
  return (unsigned short)(u >> 16);
}

// tanh(x) = 1 - 2/(exp(2x)+1); exp(2x) = exp2(x * 2*log2(e)).
// v_exp_f32 + v_rcp_f32: ~1e-7 abs err, negligible vs bf16 quantization.
__device__ __forceinline__ float tanh_fast(float v) {
  float e = __builtin_amdgcn_exp2f(v * 2.88539008177793f);
  return 1.0f - 2.0f * __builtin_amdgcn_rcpf(1.0f + e);
}

// ---------------- prep: gather+convert+init, one fused kernel ----------------
// P3 (x init) removed: gemm1 now writes x directly (no atomics).
#define P0 1048576
#define P1 1608224
#define P2 65536
#define P4 78144
#define PREP_TOTAL (P0 + P1 + P2 + P4)          // 2800480
#define PREP_BLOCKS ((PREP_TOTAL + 255) / 256)  // 10940

__global__ __launch_bounds__(256) void prep_kernel(
    const int* __restrict__ ids, const float* __restrict__ temb,
    const float* __restrict__ in_w,
    const int* __restrict__ src, const float* __restrict__ rw,
    const float* __restrict__ out_w,
    unsigned short* __restrict__ flatb, unsigned short* __restrict__ inwb,
    unsigned short* __restrict__ outwb,
    int* __restrict__ iw) {
  int i = blockIdx.x * 256 + threadIdx.x;
  if (i < P0) {
    int bt = i >> 3, d4 = i & 7;
    int id = ids[bt];
    float4 v = *(const float4*)(temb + id * 32 + d4 * 4);
    ushort4 o; o.x = f2bf(v.x); o.y = f2bf(v.y); o.z = f2bf(v.z); o.w = f2bf(v.w);
    *(ushort4*)(flatb + (size_t)i * 4) = o;
    return;
  }
  i -= P0;
  if (i < P1) {
    float4 v = ((const float4*)out_w)[i];
    ushort4 o; o.x = f2bf(v.x); o.y = f2bf(v.y); o.z = f2bf(v.z); o.w = f2bf(v.w);
    *(ushort4*)(outwb + (size_t)i * 4) = o;
    return;
  }
  i -= P1;
  if (i < P2) {
    float4 v = ((const float4*)in_w)[i];
    ushort4 o; o.x = f2bf(v.x); o.y = f2bf(v.y); o.z = f2bf(v.z); o.w = f2bf(v.w);
    *(ushort4*)(inwb + (size_t)i * 4) = o;
    return;
  }
  i -= P2;
  if (i < P4) {
    int r = i / KPAD, k = i - r * KPAD;
    int idx = 0; unsigned wb = 0;
    if (k < KDEG) {
      idx = src[r * KDEG + k];
      wb = __float_as_uint(rw[r * KDEG + k]);
    }
    iw[(size_t)i * 2] = idx;
    iw[(size_t)i * 2 + 1] = (int)wb;
  }
}

// ---------------- gemm1: x = flat @ in_w^T + in_b ---------------------------
// grid (64 m-tiles, 4 n-tiles); 4 waves split K=2048 into 512-chunks,
// LDS-reduce the four 32x32 partials. No global atomics, no x pre-init.
__global__ __launch_bounds__(256) void gemm1_kernel(
    const __bf16* __restrict__ flatb, const __bf16* __restrict__ inwb,
    const float* __restrict__ in_b, float* __restrict__ x) {
  __shared__ float red[4 * 32 * 32];   // 16 KB
  int tid = threadIdx.x;
  int wv = tid >> 6, lane = tid & 63;
  int row = lane & 31, half = lane >> 5;
  int m0 = blockIdx.x * 32;
  int n0 = blockIdx.y * 32;
  int k0 = wv * 512;
  const __bf16* ap = flatb + (size_t)(m0 + row) * TD + k0 + half * 8;
  const __bf16* bp = inwb + (size_t)(n0 + row) * TD + k0 + half * 8;
  floatx16 acc = (floatx16)0.0f;
#pragma unroll 8
  for (int s = 0; s < 32; ++s) {
    bf16x8 a = *(const bf16x8*)(ap + s * 16);
    bf16x8 b = *(const bf16x8*)(bp + s * 16);
    acc = __builtin_amdgcn_mfma_f32_32x32x16_bf16(a, b, acc, 0, 0, 0);
  }
#pragma unroll
  for (int r = 0; r < 16; ++r) {
    int mrow = (r & 3) + 8 * (r >> 2) + 4 * half;
    red[wv * 1024 + mrow * 32 + row] = acc[r];
  }
  __syncthreads();
#pragma unroll
  for (int p = 0; p < 4; ++p) {
    int idx = p * 256 + tid;
    int ml = idx >> 5, nl = idx & 31;
    float s = red[idx] + red[1024 + idx] + red[2048 + idx] + red[3072 + idx]
            + in_b[n0 + nl];
    x[(size_t)(m0 + ml) * NIN + n0 + nl] = s;
  }
}

// ---------------- rwnn: sparse DAG forward, 8 batch elems / block ------------
// 512 threads: 4 threads per node-row (batch-pairs, float2), 8 waves/CU.
__global__ __launch_bounds__(512) void rwnn_kernel(
    const float* __restrict__ x, const int* __restrict__ iw,
    unsigned short* __restrict__ hb) {
  __shared__ float vals[VALSN * 8];   // [node][batch8], 52224 B
  int tid = threadIdx.x;
  int b0 = blockIdx.x * 8;
  {
    int p = tid & 7, n = tid >> 3;           // n in 0..63
    vals[n * 8 + p] = x[(b0 + p) * NIN + n];
    vals[(n + 64) * 8 + p] = x[(b0 + p) * NIN + n + 64];
    if (tid < 16) vals[(NIN + (tid >> 3)) * 8 + (tid & 7)] = 1.0f;
  }
  __syncthreads();
  int g = tid >> 2;          // 0..127 node group
  int pq = (tid & 3) * 2;    // batch pair offset: 0,2,4,6
  int base = NIN + 2;        // 130
  int off = 0;
  for (int layer = 0; layer < 5; ++layer) {
    for (int r = g; r < HPL; r += 128) {
      const int4* q4 = (const int4*)(iw) + (size_t)(off + r) * (KPAD / 2);
      float s0 = 0.f, s1 = 0.f;
      // KPAD=48 (idx,w) pairs = 24 int4s per row; 2 pairs per int4.
#pragma unroll
      for (int k4 = 0; k4 < KPAD / 2; ++k4) {
        int4 q = q4[k4];
        float2 v0 = *(const float2*)(&vals[q.x * 8 + pq]);
        float w0 = __int_as_float(q.y);
        s0 += v0.x * w0; s1 += v0.y * w0;
        float2 v1 = *(const float2*)(&vals[q.z * 8 + pq]);
        float w1 = __int_as_float(q.w);
        s0 += v1.x * w1; s1 += v1.y * w1;
      }
      float2 o; o.x = tanh_fast(s0); o.y = tanh_fast(s1);
      *(float2*)(&vals[(base + r) * 8 + pq]) = o;
    }
    __syncthreads();
    off += HPL; base += HPL;
  }
  // output layer: rows off..off+127 (off == 1500), each g does exactly one
  {
    int r = g;
    const int4* q4 = (const int4*)(iw) + (size_t)(off + r) * (KPAD / 2);
    float s0 = 0.f, s1 = 0.f;
#pragma unroll
    for (int k4 = 0; k4 < KPAD / 2; ++k4) {
      int4 q = q4[k4];
      float2 v0 = *(const float2*)(&vals[q.x * 8 + pq]);
      float w0 = __int_as_float(q.y);
      s0 += v0.x * w0; s1 += v0.y * w0;
      float2 v1 = *(const float2*)(&vals[q.z * 8 + pq]);
      float w1 = __int_as_float(q.w);
      s0 += v1.x * w1; s1 += v1.y * w1;
    }
    hb[(b0 + pq + 0) * NOUT + r] = f2bf(tanh_fast(s0));
    hb[(b0 + pq + 1) * NOUT + r] = f2bf(tanh_fast(s1));
  }
}

// ---------------- gemm3: logits = h @ out_w^T + out_b  (MFMA 32x32x16) ------
__global__ __launch_bounds__(256) void gemm3_kernel(
    const __bf16* __restrict__ h, const __bf16* __restrict__ wv,
    const float* __restrict__ out_b, float* __restrict__ out) {
  int tid = threadIdx.x;
  int wvid = tid >> 6, lane = tid & 63;
  int row = lane & 31, half = lane >> 5;
  int m0 = blockIdx.x * 32;
  int v0 = blockIdx.y * 128 + wvid * 32;
  int vr = v0 + row;
  int vc = vr < V_SZ ? vr : V_SZ - 1;
  const __bf16* ap = h + (size_t)(m0 + row) * NOUT + half * 8;
  const __bf16* bp = wv + (size_t)vc * NOUT + half * 8;
  floatx16 acc = (floatx16)0.0f;
#pragma unroll
  for (int s = 0; s < 8; ++s) {
    bf16x8 a = *(const bf16x8*)(ap + s * 16);
    bf16x8 b = *(const bf16x8*)(bp + s * 16);
    acc = __builtin_amdgcn_mfma_f32_32x32x16_bf16(a, b, acc, 0, 0, 0);
  }
  if (vr < V_SZ) {
    float bias = out_b[vr];
#pragma unroll
    for (int r = 0; r < 16; ++r) {
      int mrow = (r & 3) + 8 * (r >> 2) + 4 * half;
      out[(size_t)(m0 + mrow) * V_SZ + vr] = acc[r] + bias;
    }
  }
}

// ---------------- launch -----------------------------------------------------
extern "C" void kernel_launch(void* const* d_in, const int* in_sizes, int n_in,
                              void* d_out, int out_size, void* d_ws, size_t ws_size,
                              hipStream_t stream) {
  const int*   ids   = (const int*)d_in[0];
  const float* temb  = (const float*)d_in[1];
  const float* in_w  = (const float*)d_in[2];
  const float* in_b  = (const float*)d_in[3];
  const int*   src   = (const int*)d_in[4];
  const float* rw    = (const float*)d_in[5];
  const float* out_w = (const float*)d_in[6];
  const float* out_b = (const float*)d_in[7];
  float* out = (float*)d_out;

  char* ws = (char*)d_ws;
  unsigned short* flatb = (unsigned short*)(ws);
  unsigned short* inwb  = (unsigned short*)(ws + 8388608);
  unsigned short* outwb = (unsigned short*)(ws + 8912896);
  float*          x     = (float*)(ws + 21778688);
  unsigned short* hb    = (unsigned short*)(ws + 22827264);
  int*            iw    = (int*)(ws + 23351552);

  prep_kernel<<<PREP_BLOCKS, 256, 0, stream>>>(ids, temb, in_w, src, rw,
                                               out_w, flatb, inwb, outwb, iw);
  gemm1_kernel<<<dim3(64, 4), 256, 0, stream>>>((const __bf16*)flatb,
                                                (const __bf16*)inwb, in_b, x);
  rwnn_kernel<<<256, 512, 0, stream>>>(x, iw, hb);
  gemm3_kernel<<<dim3(64, 393), 256, 0, stream>>>((const __bf16*)hb,
                                                  (const __bf16*)outwb, out_b, out);
}